// Round 5
// baseline (1904.513 us; speedup 1.0000x reference)
//
#include <hip/hip_runtime.h>
#include <math.h>

#define BS 128
#define NW 80
#define NF 64
#define DD 768
#define INV_TAU 100.0f

typedef unsigned short u16;
typedef unsigned int u32;
typedef __attribute__((ext_vector_type(8))) short bf16x8;
typedef __attribute__((ext_vector_type(4))) float f32x4;

__device__ __forceinline__ u16 f2bf(float x) {
    unsigned b = __float_as_uint(x);
    return (u16)((b + 0x7fffu + ((b >> 16) & 1u)) >> 16);
}
__device__ __forceinline__ float bf2f(u16 h) { return __uint_as_float(((unsigned)h) << 16); }

__device__ __forceinline__ void gload_lds16(const void* gsrc, void* ldst) {
    __builtin_amdgcn_global_load_lds(
        (const __attribute__((address_space(1))) unsigned int*)gsrc,
        (__attribute__((address_space(3))) unsigned int*)ldst, 16, 0, 0);
}

// ---------------- K1: sg = sentence_output @ global_mat_weight ----------------
__global__ __launch_bounds__(256) void k_sent_global(
    const float* __restrict__ sent, const float* __restrict__ G, float* __restrict__ sg)
{
    int idx = blockIdx.x * 256 + threadIdx.x;
    int t = idx / DD, e = idx % DD;
    const float* srow = sent + t * DD;
    float acc = 0.f;
    #pragma unroll 4
    for (int d = 0; d < DD; ++d) acc += srow[d] * G[d * DD + e];
    sg[idx] = acc;
}

// ---------------- K1b: sim = 0.25 * sg @ traj^T ----------------
__global__ __launch_bounds__(256) void k_traj_sent(
    const float* __restrict__ sg, const float* __restrict__ traj, float* __restrict__ sim)
{
    __shared__ float ss[16][33], tt[16][33];
    int tx = threadIdx.x & 15, ty = threadIdx.x >> 4;
    int t0 = blockIdx.y * 16, v0 = blockIdx.x * 16;
    float acc = 0.f;
    for (int kk = 0; kk < DD; kk += 32) {
        for (int l = threadIdx.x; l < 16 * 32; l += 256) {
            int r = l >> 5, c = l & 31;
            ss[r][c] = sg[(t0 + r) * DD + kk + c];
            tt[r][c] = traj[(v0 + r) * DD + kk + c];
        }
        __syncthreads();
        #pragma unroll
        for (int k = 0; k < 32; ++k) acc += ss[ty][k] * tt[tx][k];
        __syncthreads();
    }
    sim[(t0 + ty) * BS + v0 + tx] = 0.25f * acc;
}

// ---------------- K_prepw: Wm_pad[80][96] hi/lo (row-major, u-pad 0), Fm[64][64] hi/lo ----------------
__global__ __launch_bounds__(256) void k_prepw(
    const float* __restrict__ Wm, const float* __restrict__ Fm,
    u16* __restrict__ Wm_hi, u16* __restrict__ Wm_lo,
    u16* __restrict__ Fm_hi, u16* __restrict__ Fm_lo)
{
    int gid = blockIdx.x * 256 + threadIdx.x;
    if (gid < 80 * 96) {
        int w = gid / 96, u = gid % 96;
        float x = (u < 80) ? Wm[w * 80 + u] : 0.f;
        u16 h = f2bf(x);
        Wm_hi[gid] = h; Wm_lo[gid] = f2bf(x - bf2f(h));
    } else if (gid < 80 * 96 + 64 * 64) {
        int j = gid - 80 * 96;            // straight split of Fm row-major
        float x = Fm[j];
        u16 h = f2bf(x);
        Fm_hi[j] = h; Fm_lo[j] = f2bf(x - bf2f(h));
    }
}

// ---------------- K2b: split ff to bf16 hi/lo ----------------
__global__ __launch_bounds__(256) void k_ffsplit(
    const float* __restrict__ x, u16* __restrict__ hi, u16* __restrict__ lo)
{
    int i = blockIdx.x * 256 + threadIdx.x;
    float4 f = *(const float4*)&x[(size_t)i * 4];
    ushort4 h, l;
    h.x = f2bf(f.x); l.x = f2bf(f.x - bf2f(h.x));
    h.y = f2bf(f.y); l.y = f2bf(f.y - bf2f(h.y));
    h.z = f2bf(f.z); l.z = f2bf(f.z - bf2f(h.z));
    h.w = f2bf(f.w); l.w = f2bf(f.w - bf2f(h.w));
    *(ushort4*)&hi[(size_t)i * 4] = h;
    *(ushort4*)&lo[(size_t)i * 4] = l;
}

// ---------------- K2: wl = wf @ L via split-bf16 MFMA ----------------
__global__ __launch_bounds__(256, 2) void k_wl(
    const float* __restrict__ wf, const float* __restrict__ L,
    u16* __restrict__ wl_hi, u16* __restrict__ wl_lo)
{
    __shared__ u16 Ah[128][72], Al[128][72];
    __shared__ u16 Bh[128][72], Bl[128][72];
    const int tid = threadIdx.x;
    const int lane = tid & 63, wid = tid >> 6;
    const int m0 = blockIdx.y * 128, n0 = blockIdx.x * 128;

    f32x4 acc[2][8];
    #pragma unroll
    for (int i = 0; i < 2; ++i)
        #pragma unroll
        for (int j = 0; j < 8; ++j) acc[i][j] = (f32x4){0.f, 0.f, 0.f, 0.f};

    for (int kk = 0; kk < DD; kk += 64) {
        #pragma unroll
        for (int p = 0; p < 8; ++p) {
            int row = p * 16 + (tid >> 4), c4 = tid & 15;
            float4 v = *(const float4*)&wf[(size_t)(m0 + row) * DD + kk + c4 * 4];
            ushort4 h, l;
            h.x = f2bf(v.x); l.x = f2bf(v.x - bf2f(h.x));
            h.y = f2bf(v.y); l.y = f2bf(v.y - bf2f(h.y));
            h.z = f2bf(v.z); l.z = f2bf(v.z - bf2f(h.z));
            h.w = f2bf(v.w); l.w = f2bf(v.w - bf2f(h.w));
            *(ushort4*)&Ah[row][c4 * 4] = h;
            *(ushort4*)&Al[row][c4 * 4] = l;
        }
        #pragma unroll
        for (int p = 0; p < 8; ++p) {
            int kr = p * 8 + (tid >> 5), c4 = tid & 31;
            float4 v = *(const float4*)&L[(size_t)(kk + kr) * DD + n0 + c4 * 4];
            #pragma unroll
            for (int jj = 0; jj < 4; ++jj) {
                int n = c4 * 4 + jj;
                float x = (jj == 0) ? v.x : (jj == 1) ? v.y : (jj == 2) ? v.z : v.w;
                u16 h = f2bf(x);
                int ka = kr ^ ((n & 7) << 3);
                Bh[n][ka] = h;
                Bl[n][ka] = f2bf(x - bf2f(h));
            }
        }
        __syncthreads();
        #pragma unroll
        for (int ks = 0; ks < 2; ++ks) {
            int koff = ks * 32 + (lane >> 4) * 8;
            bf16x8 ah[2], al[2];
            #pragma unroll
            for (int i = 0; i < 2; ++i) {
                int row = wid * 32 + 16 * i + (lane & 15);
                ah[i] = *(const bf16x8*)&Ah[row][koff];
                al[i] = *(const bf16x8*)&Al[row][koff];
            }
            #pragma unroll
            for (int j = 0; j < 8; ++j) {
                int n = 16 * j + (lane & 15);
                int kb = koff ^ ((n & 7) << 3);
                bf16x8 bh = *(const bf16x8*)&Bh[n][kb];
                bf16x8 bl = *(const bf16x8*)&Bl[n][kb];
                #pragma unroll
                for (int i = 0; i < 2; ++i) {
                    acc[i][j] = __builtin_amdgcn_mfma_f32_16x16x32_bf16(ah[i], bh, acc[i][j], 0, 0, 0);
                    acc[i][j] = __builtin_amdgcn_mfma_f32_16x16x32_bf16(ah[i], bl, acc[i][j], 0, 0, 0);
                    acc[i][j] = __builtin_amdgcn_mfma_f32_16x16x32_bf16(al[i], bh, acc[i][j], 0, 0, 0);
                }
            }
        }
        __syncthreads();
    }
    #pragma unroll
    for (int i = 0; i < 2; ++i)
        #pragma unroll
        for (int j = 0; j < 8; ++j)
            #pragma unroll
            for (int r = 0; r < 4; ++r) {
                float x = acc[i][j][r];
                int row = m0 + wid * 32 + 16 * i + ((lane >> 4) << 2) + r;
                int col = n0 + 16 * j + (lane & 15);
                size_t idx = (size_t)row * DD + col;
                u16 h = f2bf(x);
                wl_hi[idx] = h;
                wl_lo[idx] = f2bf(x - bf2f(h));
            }
}

// ---------------- K3: video_word (fp32, unchanged) ----------------
__global__ __launch_bounds__(256, 2) void k_video_word(
    const float* __restrict__ wf, const float* __restrict__ traj,
    const float* __restrict__ Wl, float* __restrict__ sim)
{
    __shared__ __align__(16) float As[NW][36];
    __shared__ __align__(16) float Bs[64][36];
    __shared__ float Am[NW][65];
    __shared__ float Pm[NW][65];
    int tx = threadIdx.x & 15, ty = threadIdx.x >> 4;
    int t = blockIdx.y, v0 = blockIdx.x * 64;
    const float* wft = wf + t * NW * DD;
    float acc[5][4] = {};
    for (int kk = 0; kk < DD; kk += 32) {
        for (int l = threadIdx.x; l < NW * 32; l += 256) {
            int w = l >> 5, k = l & 31;
            As[w][k] = wft[w * DD + kk + k];
        }
        for (int l = threadIdx.x; l < 64 * 32; l += 256) {
            int v = l >> 5, k = l & 31;
            Bs[v][k] = traj[(v0 + v) * DD + kk + k];
        }
        __syncthreads();
        #pragma unroll
        for (int k = 0; k < 32; k += 4) {
            float4 a[5], b[4];
            #pragma unroll
            for (int i = 0; i < 5; ++i) a[i] = *(const float4*)&As[tx + 16 * i][k];
            #pragma unroll
            for (int j = 0; j < 4; ++j) b[j] = *(const float4*)&Bs[ty + 16 * j][k];
            #pragma unroll
            for (int i = 0; i < 5; ++i)
                #pragma unroll
                for (int j = 0; j < 4; ++j)
                    acc[i][j] += a[i].x * b[j].x + a[i].y * b[j].y + a[i].z * b[j].z + a[i].w * b[j].w;
        }
        __syncthreads();
    }
    #pragma unroll
    for (int i = 0; i < 5; ++i)
        #pragma unroll
        for (int j = 0; j < 4; ++j) Am[tx + 16 * i][ty + 16 * j] = acc[i][j];
    __syncthreads();
    if (threadIdx.x < 64) {
        int v = threadIdx.x;
        float m = -1e30f;
        for (int w = 0; w < NW; ++w) m = fmaxf(m, Am[w][v]);
        float s = 0.f;
        for (int w = 0; w < NW; ++w) { float e = __expf((Am[w][v] - m) * INV_TAU); Pm[w][v] = e; s += e; }
        float r = 1.f / s;
        for (int w = 0; w < NW; ++w) Pm[w][v] *= r;
    }
    __syncthreads();
    float mm[5][4] = {};
    for (int w = 0; w < NW; ++w) {
        float a[5], b[4];
        #pragma unroll
        for (int i = 0; i < 5; ++i) a[i] = Wl[w * NW + tx + 16 * i];
        #pragma unroll
        for (int j = 0; j < 4; ++j) b[j] = Pm[w][ty + 16 * j];
        #pragma unroll
        for (int i = 0; i < 5; ++i)
            #pragma unroll
            for (int j = 0; j < 4; ++j) mm[i][j] += a[i] * b[j];
    }
    #pragma unroll
    for (int j = 0; j < 4; ++j) {
        float p = 0.f;
        #pragma unroll
        for (int i = 0; i < 5; ++i) p += mm[i][j] * Am[tx + 16 * i][ty + 16 * j];
        for (int o = 8; o; o >>= 1) p += __shfl_xor(p, o, 16);
        if (tx == 0) sim[t * BS + v0 + ty + 16 * j] += 0.25f * p;
    }
}

// ---------------- K4: sentence_frame (fp32, unchanged) ----------------
__global__ __launch_bounds__(256, 2) void k_sent_frame(
    const float* __restrict__ sent, const float* __restrict__ ff,
    const float* __restrict__ Fl, float* __restrict__ sim)
{
    __shared__ __align__(16) float Ss[64][36];
    __shared__ __align__(16) float Fs[64][36];
    __shared__ float Bm[64][65];
    __shared__ float Pm[64][65];
    int tx = threadIdx.x & 15, ty = threadIdx.x >> 4;
    int v = blockIdx.y, t0 = blockIdx.x * 64;
    const float* ffv = ff + v * NF * DD;
    float acc[4][4] = {};
    for (int kk = 0; kk < DD; kk += 32) {
        for (int l = threadIdx.x; l < 64 * 32; l += 256) {
            int r = l >> 5, k = l & 31;
            Ss[r][k] = sent[(t0 + r) * DD + kk + k];
            Fs[r][k] = ffv[r * DD + kk + k];
        }
        __syncthreads();
        #pragma unroll
        for (int k = 0; k < 32; k += 4) {
            float4 a[4], b[4];
            #pragma unroll
            for (int i = 0; i < 4; ++i) a[i] = *(const float4*)&Ss[tx + 16 * i][k];
            #pragma unroll
            for (int j = 0; j < 4; ++j) b[j] = *(const float4*)&Fs[ty + 16 * j][k];
            #pragma unroll
            for (int i = 0; i < 4; ++i)
                #pragma unroll
                for (int j = 0; j < 4; ++j)
                    acc[i][j] += a[i].x * b[j].x + a[i].y * b[j].y + a[i].z * b[j].z + a[i].w * b[j].w;
        }
        __syncthreads();
    }
    #pragma unroll
    for (int i = 0; i < 4; ++i)
        #pragma unroll
        for (int j = 0; j < 4; ++j) Bm[tx + 16 * i][ty + 16 * j] = acc[i][j];
    __syncthreads();
    if (threadIdx.x < 64) {
        int r = threadIdx.x;
        float m = -1e30f;
        for (int f = 0; f < NF; ++f) m = fmaxf(m, Bm[r][f]);
        float s = 0.f;
        for (int f = 0; f < NF; ++f) { float e = __expf((Bm[r][f] - m) * INV_TAU); Pm[r][f] = e; s += e; }
        float rr = 1.f / s;
        for (int f = 0; f < NF; ++f) Pm[r][f] *= rr;
    }
    __syncthreads();
    float nn[4][4] = {};
    for (int f = 0; f < NF; ++f) {
        float a[4], b[4];
        #pragma unroll
        for (int i = 0; i < 4; ++i) a[i] = Pm[ty + 16 * i][f];
        #pragma unroll
        for (int j = 0; j < 4; ++j) b[j] = Fl[f * NF + tx + 16 * j];
        #pragma unroll
        for (int i = 0; i < 4; ++i)
            #pragma unroll
            for (int j = 0; j < 4; ++j) nn[i][j] += a[i] * b[j];
    }
    #pragma unroll
    for (int i = 0; i < 4; ++i) {
        float p = 0.f;
        #pragma unroll
        for (int j = 0; j < 4; ++j) p += nn[i][j] * Bm[ty + 16 * i][tx + 16 * j];
        for (int o = 8; o; o >>= 1) p += __shfl_xor(p, o, 16);
        if (tx == 0) sim[(t0 + ty + 16 * i) * BS + v] += 0.25f * p;
    }
}

// ---------------- K5: frame_word — S-GEMM + E=Wm@S, G=S@Fm^T (register-elementwise softmax) ----------------
__global__ __launch_bounds__(256, 3) void k_frame_word(
    const u16* __restrict__ wl_hi, const u16* __restrict__ wl_lo,
    const u16* __restrict__ ff_hi, const u16* __restrict__ ff_lo,
    const u16* __restrict__ Wm_hi, const u16* __restrict__ Wm_lo,
    const u16* __restrict__ Fm_hi, const u16* __restrict__ Fm_lo,
    const float* __restrict__ F2, const float* __restrict__ Wm2,
    float* __restrict__ sim)
{
    __shared__ __align__(16) union SH {
        u16 stage[18432];                       // 36864 B (GEMM phase)
        struct Post {
            u16 Swf_h[80][72], Swf_l[80][72];   // 23040: S row-major (k=f contig)
            u16 Sfw_h[64][104], Sfw_l[64][104]; // 26624: S^T (k=w/u contig, pad->96 zeroed)
            float part[2][4][80];               // 2560: [0]=rowmax parts / flvp, [1]=rowsum parts
            float rowM[80], rowRD[80];          // 640
            float wlv[64], flv[80];             // 576
            float smw[64], smf[80];             // 576
            float s2f, v2w;                     // 8   -> 54,024 B
        } post;
    } sh;

    const int tid = threadIdx.x;
    const int lane = tid & 63, wid = tid >> 6;
    const int col = lane & 15, grp = lane >> 4;
    const int v = blockIdx.x, t = blockIdx.y;
    const int myf = col + 16 * wid;             // this thread's f-column

    f32x4 acc[5], acc2[5];
    #pragma unroll
    for (int i = 0; i < 5; ++i) { acc[i] = (f32x4){0.f,0.f,0.f,0.f}; acc2[i] = (f32x4){0.f,0.f,0.f,0.f}; }

    const int r8 = lane >> 3, s8 = lane & 7;
    const int gk = s8 ^ r8;

    // ---- S-GEMM: S = wl_t[80x768] @ ff_v[64x768]^T, split-bf16 3-pass ----
    for (int kk = 0; kk < DD; kk += 64) {
        for (int seg = wid; seg < 36; seg += 4) {
            const u16* src;
            int ldsoff;
            if (seg < 10) {
                int g = seg, row = g * 8 + r8;
                src = wl_hi + (size_t)(t * NW + row) * DD + kk + gk * 8;
                ldsoff = g * 512;
            } else if (seg < 20) {
                int g = seg - 10, row = g * 8 + r8;
                src = wl_lo + (size_t)(t * NW + row) * DD + kk + gk * 8;
                ldsoff = 5120 + g * 512;
            } else if (seg < 28) {
                int g = seg - 20, row = g * 8 + r8;
                src = ff_hi + (size_t)(v * NF + row) * DD + kk + gk * 8;
                ldsoff = 10240 + g * 512;
            } else {
                int g = seg - 28, row = g * 8 + r8;
                src = ff_lo + (size_t)(v * NF + row) * DD + kk + gk * 8;
                ldsoff = 14336 + g * 512;
            }
            gload_lds16(src, (void*)&sh.stage[ldsoff]);
        }
        __syncthreads();
        const u16* st = sh.stage;
        #pragma unroll
        for (int ks = 0; ks < 2; ++ks) {
            const int sl = (ks << 2) + grp;
            bf16x8 afh[5], afl[5], bfh, bfl;
            #pragma unroll
            for (int i = 0; i < 5; ++i) {
                int row = col + 16 * i;
                int off = row * 64 + ((sl ^ (row & 7)) << 3);
                afh[i] = *(const bf16x8*)&st[off];
                afl[i] = *(const bf16x8*)&st[5120 + off];
            }
            {
                int row = col + 16 * wid;
                int off = row * 64 + ((sl ^ (row & 7)) << 3);
                bfh = *(const bf16x8*)&st[10240 + off];
                bfl = *(const bf16x8*)&st[14336 + off];
            }
            #pragma unroll
            for (int i = 0; i < 5; ++i)
                acc[i] = __builtin_amdgcn_mfma_f32_16x16x32_bf16(afh[i], bfh, acc[i], 0, 0, 0);
            #pragma unroll
            for (int i = 0; i < 5; ++i)
                acc2[i] = __builtin_amdgcn_mfma_f32_16x16x32_bf16(afh[i], bfl, acc2[i], 0, 0, 0);
            #pragma unroll
            for (int i = 0; i < 5; ++i)
                acc[i] = __builtin_amdgcn_mfma_f32_16x16x32_bf16(afl[i], bfh, acc[i], 0, 0, 0);
        }
        __syncthreads();
    }

    // ---- register S: sv[i][r] = S[w=16i+4grp+r][myf] ----
    float sv[5][4];
    #pragma unroll
    for (int i = 0; i < 5; ++i)
        #pragma unroll
        for (int r = 0; r < 4; ++r) sv[i][r] = acc[i][r] + acc2[i][r];

    // ---- pack S to LDS in both layouts; zero Sfw u-pad; row-max partials ----
    {
        int fz = tid >> 2, qz = tid & 3;
        ushort4 z = {0, 0, 0, 0};
        *(ushort4*)&sh.post.Sfw_h[fz][80 + 4 * qz] = z;
        *(ushort4*)&sh.post.Sfw_l[fz][80 + 4 * qz] = z;
    }
    #pragma unroll
    for (int i = 0; i < 5; ++i) {
        ushort4 hv, lv;
        #pragma unroll
        for (int r = 0; r < 4; ++r) {
            float x = sv[i][r];
            u16 h = f2bf(x), l = f2bf(x - bf2f(h));
            if (r == 0) { hv.x = h; lv.x = l; } else if (r == 1) { hv.y = h; lv.y = l; }
            else if (r == 2) { hv.z = h; lv.z = l; } else { hv.w = h; lv.w = l; }
            sh.post.Swf_h[16 * i + 4 * grp + r][myf] = h;
            sh.post.Swf_l[16 * i + 4 * grp + r][myf] = l;
        }
        *(ushort4*)&sh.post.Sfw_h[myf][16 * i + 4 * grp] = hv;
        *(ushort4*)&sh.post.Sfw_l[myf][16 * i + 4 * grp] = lv;
    }
    // row-max partials: per (i,r) reduce over the wave's 16 f-columns
    #pragma unroll
    for (int i = 0; i < 5; ++i)
        #pragma unroll
        for (int r = 0; r < 4; ++r) {
            float m = sv[i][r];
            m = fmaxf(m, __shfl_xor(m, 1)); m = fmaxf(m, __shfl_xor(m, 2));
            m = fmaxf(m, __shfl_xor(m, 4)); m = fmaxf(m, __shfl_xor(m, 8));
            if (col == 0) sh.post.part[0][wid][16 * i + 4 * grp + r] = m;
        }

    // ---- column softmax stats + weights, all in registers (f is wave-local) ----
    float cm = -1e30f;
    #pragma unroll
    for (int i = 0; i < 5; ++i)
        #pragma unroll
        for (int r = 0; r < 4; ++r) cm = fmaxf(cm, sv[i][r]);
    cm = fmaxf(cm, __shfl_xor(cm, 16));
    cm = fmaxf(cm, __shfl_xor(cm, 32));
    float p1[5][4], cs = 0.f;
    #pragma unroll
    for (int i = 0; i < 5; ++i)
        #pragma unroll
        for (int r = 0; r < 4; ++r) { p1[i][r] = __expf((sv[i][r] - cm) * INV_TAU); cs += p1[i][r]; }
    cs += __shfl_xor(cs, 16);
    cs += __shfl_xor(cs, 32);
    const float cRD = 1.f / cs;

    __syncthreads();   // B1: packs + rowmax partials visible

    // ---- rowM finalize (concurrent with E-GEMM) ----
    if (tid < 80) {
        float m = sh.post.part[0][0][tid];
        m = fmaxf(m, sh.post.part[0][1][tid]);
        m = fmaxf(m, sh.post.part[0][2][tid]);
        m = fmaxf(m, sh.post.part[0][3][tid]);
        sh.post.rowM[tid] = m;
    }

    // ---- E-GEMM: E[w][f] = sum_u Wm[w][u] * S[u][f]  (A=Wm_pad global, B=Sfw LDS) ----
    f32x4 e1[5], e2[5];
    #pragma unroll
    for (int i = 0; i < 5; ++i) { e1[i] = (f32x4){0.f,0.f,0.f,0.f}; e2[i] = (f32x4){0.f,0.f,0.f,0.f}; }
    #pragma unroll
    for (int ks = 0; ks < 3; ++ks) {
        const int ko = ks * 32 + grp * 8;
        bf16x8 bh = *(const bf16x8*)&sh.post.Sfw_h[myf][ko];
        bf16x8 bl = *(const bf16x8*)&sh.post.Sfw_l[myf][ko];
        bf16x8 ah[5], al[5];
        #pragma unroll
        for (int i = 0; i < 5; ++i) {
            int aaddr = (col + 16 * i) * 96 + ko;
            ah[i] = *(const bf16x8*)&Wm_hi[aaddr];
            al[i] = *(const bf16x8*)&Wm_lo[aaddr];
        }
        #pragma unroll
        for (int i = 0; i < 5; ++i)
            e1[i] = __builtin_amdgcn_mfma_f32_16x16x32_bf16(ah[i], bh, e1[i], 0, 0, 0);
        #pragma unroll
        for (int i = 0; i < 5; ++i)
            e2[i] = __builtin_amdgcn_mfma_f32_16x16x32_bf16(ah[i], bl, e2[i], 0, 0, 0);
        #pragma unroll
        for (int i = 0; i < 5; ++i)
            e1[i] = __builtin_amdgcn_mfma_f32_16x16x32_bf16(al[i], bh, e1[i], 0, 0, 0);
    }
    // wlv[f] = cRD * sum_w p1[w] * E[w][f]
    {
        float p = 0.f;
        #pragma unroll
        for (int i = 0; i < 5; ++i)
            #pragma unroll
            for (int r = 0; r < 4; ++r) p += p1[i][r] * (e1[i][r] + e2[i][r]);
        p += __shfl_xor(p, 16);
        p += __shfl_xor(p, 32);
        if (lane < 16) sh.post.wlv[myf] = p * cRD;
    }

    __syncthreads();   // B2: rowM ready

    // ---- row softmax weights p2 + sum partials ----
    float p2[5][4];
    #pragma unroll
    for (int i = 0; i < 5; ++i)
        #pragma unroll
        for (int r = 0; r < 4; ++r) {
            float Mw = sh.post.rowM[16 * i + 4 * grp + r];
            p2[i][r] = __expf((sv[i][r] - Mw) * INV_TAU);
            float s = p2[i][r];
            s += __shfl_xor(s, 1); s += __shfl_xor(s, 2);
            s += __shfl_xor(s, 4); s += __shfl_xor(s, 8);
            if (col == 0) sh.post.part[1][wid][16 * i + 4 * grp + r] = s;
        }

    __syncthreads();   // B3: sum partials visible

    if (tid < 80)
        sh.post.rowRD[tid] = 1.f / (sh.post.part[1][0][tid] + sh.post.part[1][1][tid]
                                  + sh.post.part[1][2][tid] + sh.post.part[1][3][tid]);

    // ---- G-GEMM: G[w][f] = sum_f' S[w][f'] * Fm[f][f']  (A=Swf LDS, B=Fm global) ----
    f32x4 g1[5], g2[5];
    #pragma unroll
    for (int i = 0; i < 5; ++i) { g1[i] = (f32x4){0.f,0.f,0.f,0.f}; g2[i] = (f32x4){0.f,0.f,0.f,0.f}; }
    #pragma unroll
    for (int ks = 0; ks < 2; ++ks) {
        const int ko = ks * 32 + grp * 8;
        bf16x8 bh = *(const bf16x8*)&Fm_hi[myf * 64 + ko];
        bf16x8 bl = *(const bf16x8*)&Fm_lo[myf * 64 + ko];
        bf16x8 ah[5], al[5];
        #pragma unroll
        for (int i = 0; i < 5; ++i) {
            int aaddr = (col + 16 * i) * 72 + ko;
            ah[i] = *(const bf16x8*)&sh.post.Swf_h[0][aaddr];
            al[i] = *(const bf16x8*)&sh.post.Swf_l[0][aaddr];
        }
        #pragma unroll
        for (int i = 0; i < 5; ++i)
            g1[i] = __builtin_amdgcn_mfma_f32_16x16x32_bf16(ah[i], bh, g1[i], 0, 0, 0);
        #pragma unroll
        for (int i = 0; i < 5; ++i)
            g2[i] = __builtin_amdgcn_mfma_f32_16x16x32_bf16(ah[i], bl, g2[i], 0, 0, 0);
        #pragma unroll
        for (int i = 0; i < 5; ++i)
            g1[i] = __builtin_amdgcn_mfma_f32_16x16x32_bf16(al[i], bh, g1[i], 0, 0, 0);
    }
    // flv partials: sum over this wave's 16 f-columns of p2*G -> part[0] (reused)
    #pragma unroll
    for (int i = 0; i < 5; ++i)
        #pragma unroll
        for (int r = 0; r < 4; ++r) {
            float p = p2[i][r] * (g1[i][r] + g2[i][r]);
            p += __shfl_xor(p, 1); p += __shfl_xor(p, 2);
            p += __shfl_xor(p, 4); p += __shfl_xor(p, 8);
            if (col == 0) sh.post.part[0][wid][16 * i + 4 * grp + r] = p;
        }

    __syncthreads();   // B4: flv partials + rowRD visible

    if (tid < 80)
        sh.post.flv[tid] = sh.post.rowRD[tid] * (sh.post.part[0][0][tid] + sh.post.part[0][1][tid]
                                               + sh.post.part[0][2][tid] + sh.post.part[0][3][tid]);

    __syncthreads();   // B5: wlv/flv final

    // ---- final softmaxes (wave-parallel) ----
    if (wid == 0) {
        float x = sh.post.wlv[lane];
        float m = x;
        #pragma unroll
        for (int o = 32; o; o >>= 1) m = fmaxf(m, __shfl_xor(m, o));
        float e = __expf((x - m) * INV_TAU);
        float s = e;
        #pragma unroll
        for (int o = 32; o; o >>= 1) s += __shfl_xor(s, o);
        sh.post.smw[lane] = e / s;
    } else if (wid == 1) {
        float x0 = sh.post.flv[lane];
        float x1 = (lane < 16) ? sh.post.flv[64 + lane] : -1e30f;
        float m = fmaxf(x0, x1);
        #pragma unroll
        for (int o = 32; o; o >>= 1) m = fmaxf(m, __shfl_xor(m, o));
        float e0 = __expf((x0 - m) * INV_TAU);
        float e1 = (lane < 16) ? __expf((x1 - m) * INV_TAU) : 0.f;
        float s = e0 + e1;
        #pragma unroll
        for (int o = 32; o; o >>= 1) s += __shfl_xor(s, o);
        sh.post.smf[lane] = e0 / s;
        if (lane < 16) sh.post.smf[64 + lane] = e1 / s;
    }
    __syncthreads();   // B6

    if (wid == 0) {                 // sent2frame
        float g = 0.f;
        for (int f = 0; f < NF; ++f) g += sh.post.smw[f] * F2[f * NF + lane];
        float p = g * sh.post.wlv[lane];
        #pragma unroll
        for (int o = 32; o; o >>= 1) p += __shfl_xor(p, o);
        if (lane == 0) sh.post.s2f = p;
    } else if (wid == 1) {          // video2word
        float g = 0.f;
        for (int w = 0; w < NW; ++w) g += sh.post.smf[w] * Wm2[w * NW + lane];
        float p = g * sh.post.flv[lane];
        if (lane < 16) {
            float g2 = 0.f;
            for (int w = 0; w < NW; ++w) g2 += sh.post.smf[w] * Wm2[w * NW + 64 + lane];
            p += g2 * sh.post.flv[64 + lane];
        }
        #pragma unroll
        for (int o = 32; o; o >>= 1) p += __shfl_xor(p, o);
        if (lane == 0) sh.post.v2w = p;
    }
    __syncthreads();   // B7
    if (tid == 0) sim[t * BS + v] += 0.125f * (sh.post.s2f + sh.post.v2w);
}

// ---------------- K6: loss from sim ----------------
__global__ __launch_bounds__(256) void k_loss(const float* __restrict__ sim, float* __restrict__ out)
{
    __shared__ float S[BS][BS + 1];
    __shared__ float lr[BS], lc[BS];
    for (int l = threadIdx.x; l < BS * BS; l += 256) {
        int r = l >> 7, c = l & 127;
        S[r][c] = sim[l];
    }
    __syncthreads();
    int tid = threadIdx.x;
    if (tid < BS) {
        float m = -1e30f;
        for (int c = 0; c < BS; ++c) m = fmaxf(m, S[tid][c]);
        float s = 0.f;
        for (int c = 0; c < BS; ++c) s += __expf(S[tid][c] - m);
        lr[tid] = m + __logf(s);
    } else {
        int c = tid - BS;
        float m = -1e30f;
        for (int r = 0; r < BS; ++r) m = fmaxf(m, S[r][c]);
        float s = 0.f;
        for (int r = 0; r < BS; ++r) s += __expf(S[r][c] - m);
        lc[c] = m + __logf(s);
    }
    __syncthreads();
    if (tid == 0) {
        float a = 0.f;
        for (int i = 0; i < BS; ++i) a += S[i][i] - 0.5f * lr[i] - 0.5f * lc[i];
        out[0] = -a / (float)BS;
    }
}

extern "C" void kernel_launch(void* const* d_in, const int* in_sizes, int n_in,
                              void* d_out, int out_size, void* d_ws, size_t ws_size,
                              hipStream_t stream)
{
    const float* traj = (const float*)d_in[0];
    const float* ff   = (const float*)d_in[1];
    const float* sent = (const float*)d_in[2];
    const float* wf   = (const float*)d_in[3];
    const float* G    = (const float*)d_in[4];
    const float* Wl   = (const float*)d_in[5];
    const float* Fl   = (const float*)d_in[6];
    const float* L    = (const float*)d_in[7];
    const float* Fm   = (const float*)d_in[8];
    const float* Wm   = (const float*)d_in[9];
    const float* F2   = (const float*)d_in[10];
    const float* Wm2  = (const float*)d_in[11];
    float* out = (float*)d_out;
    char* base = (char*)d_ws;

    // ws layout (bytes)
    float* sg     = (float*)(base);                 // 393216
    float* sim    = (float*)(base + 393216);        // 65536
    u16*   wl_hi  = (u16*)(base + 458752);          // 15728640
    u16*   wl_lo  = (u16*)(base + 16187392);        // 15728640
    u16*   ff_hi  = (u16*)(base + 31916032);        // 12582912
    u16*   ff_lo  = (u16*)(base + 44498944);        // 12582912
    u16*   Wm_hi  = (u16*)(base + 57081856);        // 15360
    u16*   Wm_lo  = (u16*)(base + 57097216);        // 15360
    u16*   Fm_hi  = (u16*)(base + 57112576);        // 8192
    u16*   Fm_lo  = (u16*)(base + 57120768);        // 8192 -> 57128960 total

    hipLaunchKernelGGL(k_sent_global, dim3(BS * DD / 256), dim3(256), 0, stream, sent, G, sg);
    hipLaunchKernelGGL(k_traj_sent, dim3(8, 8), dim3(256), 0, stream, sg, traj, sim);
    hipLaunchKernelGGL(k_prepw, dim3(46), dim3(256), 0, stream, Wm, Fm, Wm_hi, Wm_lo, Fm_hi, Fm_lo);
    hipLaunchKernelGGL(k_ffsplit, dim3(BS * NF * DD / 1024), dim3(256), 0, stream, ff, ff_hi, ff_lo);
    hipLaunchKernelGGL(k_wl, dim3(6, 80), dim3(256), 0, stream, wf, L, wl_hi, wl_lo);
    hipLaunchKernelGGL(k_video_word, dim3(2, BS), dim3(256), 0, stream, wf, traj, Wl, sim);
    hipLaunchKernelGGL(k_sent_frame, dim3(2, BS), dim3(256), 0, stream, sent, ff, Fl, sim);
    hipLaunchKernelGGL(k_frame_word, dim3(BS, BS), dim3(256), 0, stream,
                       wl_hi, wl_lo, ff_hi, ff_lo, Wm_hi, Wm_lo, Fm_hi, Fm_lo, F2, Wm2, sim);
    hipLaunchKernelGGL(k_loss, dim3(1), dim3(256), 0, stream, sim, out);
}